// Round 5
// baseline (362.085 us; speedup 1.0000x reference)
//
#include <hip/hip_runtime.h>
#include <hip/hip_cooperative_groups.h>
#include <cfloat>
#include <math.h>

namespace cg = cooperative_groups;

#define BINS   50
#define NB     256          // buckets == grid blocks
#define NTH    1024         // threads per block (16 waves)
#define SWORDS 12208        // ceil(24415/2) u16-packed slice bins (payload = flat>>8 < 24415)
#define NQRB   16           // blocks doing marginal histograms

typedef float nfloat4 __attribute__((ext_vector_type(4)));

// samples = z @ L^T + mean (L lower-triangular row-major 4x4) — bit-identical
// to the R1..R4-passing version (absmax == 0).
__device__ __forceinline__ void sample4(nfloat4 zv, const float* L, const float* M,
                                        float& s0, float& s1, float& s2, float& s3) {
  s0 = L[0] * zv.x + M[0];
  s1 = fmaf(L[5], zv.y, L[4] * zv.x) + M[1];
  s2 = fmaf(L[10], zv.z, fmaf(L[9], zv.y, L[8] * zv.x)) + M[2];
  s3 = fmaf(L[15], zv.w, fmaf(L[14], zv.z, fmaf(L[13], zv.y, L[12] * zv.x))) + M[3];
}

// One cooperative kernel: 9 phases separated by grid.sync().
// All cross-block communication is per-block partial arrays + plain stores
// (NO global atomics — R2 showed device atomics bypass L2 and hit the fabric).
__global__ void __launch_bounds__(NTH)
k_mega(const float* __restrict__ q, const float* __restrict__ r,
       const float* __restrict__ z, int N, int S, char* ws, float* out)
{
  // -------- workspace layout (12.9 MB total) --------
  double*   Bpart    = (double*)ws;                        // [14][256] cov partials
  float*    QRmm     = (float*)(ws + 28672);               // [4][256] qmn,qmx,rmn,rmx
  float*    Spart    = (float*)(ws + 32768);               // [2][256] sample min/max
  float*    meanL    = (float*)(ws + 34816);               // mean[4],L[16],qlo,qsc,rlo,rsc
  unsigned* total    = (unsigned*)(ws + 34944);            // [256] bucket totals
  double*   sumJpart = (double*)(ws + 35968);              // [256] entropy partials
  unsigned* Cnt      = (unsigned*)(ws + 38016);            // [256 blk][256 bucket]
  unsigned* Woff     = (unsigned*)(ws + 300160);           // [256 blk][256 bucket]
  unsigned* Qpart    = (unsigned*)(ws + 562304);           // [16][2500]
  unsigned* Rpart    = (unsigned*)(ws + 722304);           // [16][2500]
  unsigned* keys     = (unsigned*)(ws + 882304);           // [2M] flat bin ids (8 MB)
  unsigned short* payload = (unsigned short*)(ws + 8882304); // [2M] (4 MB)

  __shared__ __align__(16) unsigned shist[SWORDS];  // 48832 B, multi-purpose
  __shared__ unsigned s_scan[NB];
  __shared__ unsigned s_aux[NB];
  __shared__ double   sredd[48];
  __shared__ float    sredf[32];
  __shared__ float    sf[8];

  cg::grid_group grid = cg::this_grid();
  const int tid  = threadIdx.x;
  const int bid  = blockIdx.x;
  const int lane = tid & 63;
  const int wid  = tid >> 6;

  //================ Phase 1: cov raw moments + q/r minmax (partials) ======
  {
    double a[14] = {0,0,0,0,0,0,0,0,0,0,0,0,0,0};
    float qmn = FLT_MAX, qmx = -FLT_MAX, rmn = FLT_MAX, rmx = -FLT_MAX;
    int stride = NB * NTH;
    for (int i = bid * NTH + tid; i < N; i += stride) {
      float2 qv = ((const float2*)q)[i];
      float2 rv = ((const float2*)r)[i];
      qmn = fminf(qmn, fminf(qv.x, qv.y)); qmx = fmaxf(qmx, fmaxf(qv.x, qv.y));
      rmn = fminf(rmn, fminf(rv.x, rv.y)); rmx = fmaxf(rmx, fmaxf(rv.x, rv.y));
      double x0 = qv.x, x1 = qv.y, x2 = rv.x, x3 = rv.y;
      a[0] += x0; a[1] += x1; a[2] += x2; a[3] += x3;
      a[4] += x0*x0; a[5] += x0*x1; a[6] += x0*x2; a[7] += x0*x3;
      a[8] += x1*x1; a[9] += x1*x2; a[10] += x1*x3;
      a[11] += x2*x2; a[12] += x2*x3; a[13] += x3*x3;
    }
    double* covred = (double*)shist;   // [16][14] wave partials
    for (int j = 0; j < 14; j++) {
      double v = a[j];
      for (int o = 32; o > 0; o >>= 1) v += __shfl_down(v, o);
      if (lane == 0) covred[wid*14 + j] = v;
    }
    for (int o = 32; o > 0; o >>= 1) {
      qmn = fminf(qmn, __shfl_down(qmn, o)); qmx = fmaxf(qmx, __shfl_down(qmx, o));
      rmn = fminf(rmn, __shfl_down(rmn, o)); rmx = fmaxf(rmx, __shfl_down(rmx, o));
    }
    if (lane == 0) { sredf[wid] = qmn; sredd[32+wid] = (double)qmx;  // stash qmx in sredd hi
                     s_scan[wid] = __float_as_uint(rmn); s_aux[wid] = __float_as_uint(rmx); }
    __syncthreads();
    if (tid < 14) {
      double s = 0;
      for (int w = 0; w < 16; w++) s += covred[w*14 + tid];
      Bpart[tid*NB + bid] = s;
    } else if (tid >= 16 && tid < 20) {
      int k = tid - 16;  // 0:qmn 1:qmx 2:rmn 3:rmx
      float v;
      if (k == 0) { v = sredf[0];  for (int w=1;w<16;w++) v = fminf(v, sredf[w]); }
      else if (k == 1) { v = (float)sredd[32]; for (int w=1;w<16;w++) v = fmaxf(v, (float)sredd[32+w]); }
      else if (k == 2) { v = __uint_as_float(s_scan[0]); for (int w=1;w<16;w++) v = fminf(v, __uint_as_float(s_scan[w])); }
      else { v = __uint_as_float(s_aux[0]); for (int w=1;w<16;w++) v = fmaxf(v, __uint_as_float(s_aux[w])); }
      QRmm[k*NB + bid] = v;
    }
  }
  grid.sync(); // ---- 1

  //================ Phase 2: block 0 reduces partials + Cholesky =========
  if (bid == 0) {
    if (tid < 14) {
      double s = 0;
      const double* row = Bpart + tid*NB;
      for (int b = 0; b < NB; b++) s += row[b];
      sredd[tid] = s;
    } else if (tid >= 16 && tid < 20) {
      int k = tid - 16;
      const float* row = QRmm + k*NB;
      float v = row[0];
      if (k == 0 || k == 2) { for (int b = 1; b < NB; b++) v = fminf(v, row[b]); }
      else                  { for (int b = 1; b < NB; b++) v = fmaxf(v, row[b]); }
      sf[k] = v;
    }
    __syncthreads();
    if (tid == 0) {
      double mean[4];
      for (int j = 0; j < 4; j++) mean[j] = sredd[j] / (double)N;
      double cov[4][4]; int t4 = 4;
      for (int i = 0; i < 4; i++)
        for (int j = i; j < 4; j++) {
          double c = (sredd[t4] - (double)N * mean[i] * mean[j]) / (double)(N - 1);
          if (i == j) c += 1e-6;
          cov[i][j] = c; cov[j][i] = c; t4++;
        }
      double L[4][4] = {};
      for (int i = 0; i < 4; i++)
        for (int j = 0; j <= i; j++) {
          double s = cov[i][j];
          for (int k = 0; k < j; k++) s -= L[i][k] * L[j][k];
          if (i == j) L[i][j] = sqrt(s);
          else        L[i][j] = s / L[j][j];
        }
      for (int i = 0; i < 4; i++) {
        meanL[i] = (float)mean[i];
        for (int j = 0; j < 4; j++) meanL[4 + i*4 + j] = (float)L[i][j];
      }
      float qlo = sf[0], qhi = sf[1], rlo = sf[2], rhi = sf[3];
      meanL[20] = qlo; meanL[21] = (float)BINS / (qhi - qlo);
      meanL[22] = rlo; meanL[23] = (float)BINS / (rhi - rlo);
    }
  }
  grid.sync(); // ---- 2

  //================ Phase 3: sample minmax (all) + histQR (blocks<16) ====
  {
    float l[16], m[4];
    for (int i = 0; i < 16; i++) l[i] = meanL[4 + i];
    for (int i = 0; i < 4;  i++) m[i] = meanL[i];
    float mn = FLT_MAX, mx = -FLT_MAX;
    const nfloat4* z4 = (const nfloat4*)z;
    int stride = NB * NTH;
    for (int i = bid * NTH + tid; i < S; i += stride) {
      nfloat4 zv = z4[i];
      float s0, s1, s2, s3; sample4(zv, l, m, s0, s1, s2, s3);
      mn = fminf(mn, fminf(fminf(s0, s1), fminf(s2, s3)));
      mx = fmaxf(mx, fmaxf(fmaxf(s0, s1), fmaxf(s2, s3)));
    }
    for (int o = 32; o > 0; o >>= 1) {
      mn = fminf(mn, __shfl_down(mn, o)); mx = fmaxf(mx, __shfl_down(mx, o));
    }
    if (lane == 0) { sredf[wid] = mn; sredf[16 + wid] = mx; }
    __syncthreads();
    if (tid == 0) {
      float m1 = sredf[0], m2 = sredf[16];
      for (int w = 1; w < 16; w++) { m1 = fminf(m1, sredf[w]); m2 = fmaxf(m2, sredf[16+w]); }
      Spart[bid] = m1; Spart[NB + bid] = m2;
    }
    if (bid < NQRB) {   // marginal histograms, 16 partials
      int* shQ = (int*)shist; int* shR = (int*)(shist + 2500);
      for (int i = tid; i < 2500; i += NTH) { shQ[i] = 0; shR[i] = 0; }
      __syncthreads();
      float qlo = meanL[20], qsc = meanL[21], rlo = meanL[22], rsc = meanL[23];
      int stride2 = NQRB * NTH;
      for (int i = bid * NTH + tid; i < N; i += stride2) {
        float2 qv = ((const float2*)q)[i];
        float2 rv = ((const float2*)r)[i];
        int a = min(max((int)floorf((qv.x - qlo) * qsc), 0), BINS - 1);
        int b = min(max((int)floorf((qv.y - qlo) * qsc), 0), BINS - 1);
        atomicAdd(&shQ[a*BINS + b], 1);
        a = min(max((int)floorf((rv.x - rlo) * rsc), 0), BINS - 1);
        b = min(max((int)floorf((rv.y - rlo) * rsc), 0), BINS - 1);
        atomicAdd(&shR[a*BINS + b], 1);
      }
      __syncthreads();
      for (int i = tid; i < 2500; i += NTH) {
        Qpart[bid*2500 + i] = (unsigned)shQ[i];
        Rpart[bid*2500 + i] = (unsigned)shR[i];
      }
    }
  }
  grid.sync(); // ---- 3

  //================ Phase 4: partition — keys + per-block bucket counts ==
  {
    // every block redundantly reduces Spart -> lo, scale
    float mn = FLT_MAX, mx = -FLT_MAX;
    if (tid < NB) { mn = Spart[tid]; mx = Spart[NB + tid]; }
    for (int o = 32; o > 0; o >>= 1) {
      mn = fminf(mn, __shfl_down(mn, o)); mx = fmaxf(mx, __shfl_down(mx, o));
    }
    if (lane == 0 && wid < 4) { sredf[wid] = mn; sredf[16 + wid] = mx; }
    __syncthreads();
    if (tid == 0) {
      float m1 = fminf(fminf(sredf[0], sredf[1]), fminf(sredf[2], sredf[3]));
      float m2 = fmaxf(fmaxf(sredf[16], sredf[17]), fmaxf(sredf[18], sredf[19]));
      sf[0] = m1; sf[1] = (float)BINS / (m2 - m1);
    }
    __syncthreads();
    float lo_s = sf[0], sc_s = sf[1];
    float l[16], m[4];
    for (int i = 0; i < 16; i++) l[i] = meanL[4 + i];
    for (int i = 0; i < 4;  i++) m[i] = meanL[i];
    if (tid < NB) s_scan[tid] = 0;
    __syncthreads();
    int chunk = (S + NB - 1) / NB;
    int a0 = bid * chunk, a1 = min(a0 + chunk, S);
    const nfloat4* z4 = (const nfloat4*)z;
    for (int i = a0 + tid; i < a1; i += NTH) {
      nfloat4 zv = z4[i];
      float s0, s1, s2, s3; sample4(zv, l, m, s0, s1, s2, s3);
      int i0 = min(max((int)floorf((s0 - lo_s) * sc_s), 0), BINS - 1);
      int i1 = min(max((int)floorf((s1 - lo_s) * sc_s), 0), BINS - 1);
      int i2 = min(max((int)floorf((s2 - lo_s) * sc_s), 0), BINS - 1);
      int i3 = min(max((int)floorf((s3 - lo_s) * sc_s), 0), BINS - 1);
      unsigned flat = (unsigned)(((i0*BINS + i1)*BINS + i2)*BINS + i3);
      keys[i] = flat;
      atomicAdd(&s_scan[flat & 255u], 1u);   // bucket = flat mod 256 (balanced)
    }
    __syncthreads();
    if (tid < NB) Cnt[bid*NB + tid] = s_scan[tid];
  }
  grid.sync(); // ---- 4

  //================ Phase 5: per-bucket scan over blocks =================
  {
    unsigned v = (tid < NB) ? Cnt[tid*NB + bid] : 0u;
    if (tid < NB) s_scan[tid] = v;
    __syncthreads();
    for (int off = 1; off < NB; off <<= 1) {
      unsigned x = (tid < NB && tid >= off) ? s_scan[tid - off] : 0u;
      __syncthreads();
      if (tid < NB) s_scan[tid] += x;
      __syncthreads();
    }
    if (tid < NB) Woff[tid*NB + bid] = s_scan[tid] - v;   // exclusive
    if (tid == NB - 1) total[bid] = s_scan[NB - 1];
  }
  grid.sync(); // ---- 5

  //================ Phase 6: scatter payloads bucket-contiguously ========
  {
    unsigned v = (tid < NB) ? total[tid] : 0u;
    if (tid < NB) s_scan[tid] = v;
    __syncthreads();
    for (int off = 1; off < NB; off <<= 1) {
      unsigned x = (tid < NB && tid >= off) ? s_scan[tid - off] : 0u;
      __syncthreads();
      if (tid < NB) s_scan[tid] += x;
      __syncthreads();
    }
    if (tid < NB) s_aux[tid] = (s_scan[tid] - v) + Woff[bid*NB + tid];
    __syncthreads();
    if (tid < NB) s_scan[tid] = 0;   // cursors
    __syncthreads();
    int chunk = (S + NB - 1) / NB;
    int a0 = bid * chunk, a1 = min(a0 + chunk, S);
    for (int i = a0 + tid; i < a1; i += NTH) {
      unsigned flat = keys[i];
      unsigned b = flat & 255u;
      unsigned off = atomicAdd(&s_scan[b], 1u);
      payload[s_aux[b] + off] = (unsigned short)(flat >> 8);
    }
  }
  grid.sync(); // ---- 6

  //================ Phase 7: per-bucket LDS histogram + entropy ==========
  {
    unsigned v = (tid < NB) ? total[tid] : 0u;
    if (tid < NB) s_scan[tid] = v;
    __syncthreads();
    for (int off = 1; off < NB; off <<= 1) {
      unsigned x = (tid < NB && tid >= off) ? s_scan[tid - off] : 0u;
      __syncthreads();
      if (tid < NB) s_scan[tid] += x;
      __syncthreads();
    }
    unsigned tot  = total[bid];
    unsigned base = s_scan[bid] - tot;
    __syncthreads();
    for (int i = tid; i < SWORDS; i += NTH) shist[i] = 0u;
    __syncthreads();
    for (unsigned k = tid; k < tot; k += NTH) {
      unsigned p = payload[base + k];
      atomicAdd(&shist[p >> 1], (p & 1u) ? 65536u : 1u);
    }
    __syncthreads();
    double local = 0.0;
    for (int i = tid; i < SWORDS; i += NTH) {
      unsigned w = shist[i];
      unsigned c0 = w & 0xFFFFu, c1 = w >> 16;
      if (c0 > 1) local += (double)c0 * log((double)c0);
      if (c1 > 1) local += (double)c1 * log((double)c1);
    }
    for (int o = 32; o > 0; o >>= 1) local += __shfl_down(local, o);
    if (lane == 0) sredd[wid] = local;
    __syncthreads();
    if (tid == 0) {
      double s = 0; for (int w = 0; w < 16; w++) s += sredd[w];
      sumJpart[bid] = s;
    }
  }
  grid.sync(); // ---- 7

  //================ Phase 8: block 0 — final reduction + output ==========
  if (bid == 0) {
    double v = (tid < NB) ? sumJpart[tid] : 0.0;
    for (int o = 32; o > 0; o >>= 1) v += __shfl_down(v, o);
    if (lane == 0) sredd[wid] = v;
    __syncthreads();
    double lq = 0.0, lr = 0.0;
    for (int bin = tid; bin < 2500; bin += NTH) {
      unsigned cq = 0, cr = 0;
      for (int k = 0; k < NQRB; k++) { cq += Qpart[k*2500 + bin]; cr += Rpart[k*2500 + bin]; }
      if (cq > 1) lq += (double)cq * log((double)cq);
      if (cr > 1) lr += (double)cr * log((double)cr);
    }
    for (int o = 32; o > 0; o >>= 1) { lq += __shfl_down(lq, o); lr += __shfl_down(lr, o); }
    if (lane == 0) { sredd[16 + wid] = lq; sredd[32 + wid] = lr; }
    __syncthreads();
    if (tid == 0) {
      double sJ = 0, sq = 0, sr = 0;
      for (int w = 0; w < 16; w++) { sJ += sredd[w]; sq += sredd[16+w]; sr += sredd[32+w]; }
      double HT = log((double)N) - sq / (double)N;
      double HI = log((double)N) - sr / (double)N;
      double HJ = log((double)S) - sJ / (double)S;
      double val = HJ / (HT + HI);
      val = val < 0.0 ? 0.0 : (val > 1.0 ? 1.0 : val);
      out[0] = (float)val;
    }
  }
}

extern "C" void kernel_launch(void* const* d_in, const int* in_sizes, int n_in,
                              void* d_out, int out_size, void* d_ws, size_t ws_size,
                              hipStream_t stream) {
  const float* q = (const float*)d_in[0];
  const float* r = (const float*)d_in[1];
  const float* z = (const float*)d_in[2];
  int N = in_sizes[0] / 2;   // 200000 rows
  int S = in_sizes[2] / 4;   // 2000000 samples
  char* ws = (char*)d_ws;    // needs 12,882,304 B
  float* out = (float*)d_out;
  void* args[] = { (void*)&q, (void*)&r, (void*)&z, (void*)&N, (void*)&S,
                   (void*)&ws, (void*)&out };
  hipLaunchCooperativeKernel((const void*)k_mega, dim3(NB), dim3(NTH),
                             args, 0, stream);
}

// Round 6
// 203.006 us; speedup vs baseline: 1.7836x; 1.7836x over previous
//
#include <hip/hip_runtime.h>
#include <cfloat>
#include <math.h>

#define BINS   50
#define NB     256          // buckets AND partition blocks
#define NQRB   16           // blocks doing marginal histograms
#define SWORDS 12208        // ceil(24415/2) u16-packed slice bins (payload = flat>>8 < 24415)
#define KCAP   7936         // >= ceil(2e6/256) = 7813 keys per block

typedef float nfloat4 __attribute__((ext_vector_type(4)));

// ---- monotone float<->uint encoding for atomic min/max on floats ----
__device__ __forceinline__ unsigned encf(float f) {
  unsigned u = __float_as_uint(f);
  return (u & 0x80000000u) ? ~u : (u | 0x80000000u);
}
__device__ __forceinline__ float decf(unsigned u) {
  unsigned v = (u & 0x80000000u) ? (u & 0x7FFFFFFFu) : ~u;
  return __uint_as_float(v);
}

// samples = z @ L^T + mean (bit-identical to all passing rounds)
__device__ __forceinline__ void sample4(nfloat4 zv, const float* L, const float* M,
                                        float& s0, float& s1, float& s2, float& s3) {
  s0 = L[0] * zv.x + M[0];
  s1 = fmaf(L[5], zv.y, L[4] * zv.x) + M[1];
  s2 = fmaf(L[10], zv.z, fmaf(L[9], zv.y, L[8] * zv.x)) + M[2];
  s3 = fmaf(L[15], zv.w, fmaf(L[14], zv.z, fmaf(L[13], zv.y, L[12] * zv.x))) + M[3];
}

// ============ k_A: cov raw moments + q/r min-max partials (no atomics)
__global__ void __launch_bounds__(256)
k_A(const float* __restrict__ q, const float* __restrict__ r, int n,
    double* Bpart, float* QRmm) {
  double a[14] = {0,0,0,0,0,0,0,0,0,0,0,0,0,0};
  float qmn = FLT_MAX, qmx = -FLT_MAX, rmn = FLT_MAX, rmx = -FLT_MAX;
  int stride = gridDim.x * blockDim.x;
  for (int i = blockIdx.x * blockDim.x + threadIdx.x; i < n; i += stride) {
    float2 qv = ((const float2*)q)[i];
    float2 rv = ((const float2*)r)[i];
    qmn = fminf(qmn, fminf(qv.x, qv.y)); qmx = fmaxf(qmx, fmaxf(qv.x, qv.y));
    rmn = fminf(rmn, fminf(rv.x, rv.y)); rmx = fmaxf(rmx, fmaxf(rv.x, rv.y));
    double x0 = qv.x, x1 = qv.y, x2 = rv.x, x3 = rv.y;
    a[0] += x0; a[1] += x1; a[2] += x2; a[3] += x3;
    a[4] += x0*x0; a[5] += x0*x1; a[6] += x0*x2; a[7] += x0*x3;
    a[8] += x1*x1; a[9] += x1*x2; a[10] += x1*x3;
    a[11] += x2*x2; a[12] += x2*x3; a[13] += x3*x3;
  }
  __shared__ double sh[4][14];
  __shared__ float shf[4][4];
  int lane = threadIdx.x & 63, wid = threadIdx.x >> 6;
  for (int j = 0; j < 14; j++) {
    double v = a[j];
    for (int o = 32; o > 0; o >>= 1) v += __shfl_down(v, o);
    if (lane == 0) sh[wid][j] = v;
  }
  for (int o = 32; o > 0; o >>= 1) {
    qmn = fminf(qmn, __shfl_down(qmn, o)); qmx = fmaxf(qmx, __shfl_down(qmx, o));
    rmn = fminf(rmn, __shfl_down(rmn, o)); rmx = fmaxf(rmx, __shfl_down(rmx, o));
  }
  if (lane == 0) { shf[wid][0] = qmn; shf[wid][1] = qmx; shf[wid][2] = rmn; shf[wid][3] = rmx; }
  __syncthreads();
  if (threadIdx.x < 14) {
    double t = sh[0][threadIdx.x] + sh[1][threadIdx.x] + sh[2][threadIdx.x] + sh[3][threadIdx.x];
    Bpart[threadIdx.x * NB + blockIdx.x] = t;
  } else if (threadIdx.x >= 16 && threadIdx.x < 20) {
    int k = threadIdx.x - 16;
    float v;
    if (k == 0)      v = fminf(fminf(shf[0][0], shf[1][0]), fminf(shf[2][0], shf[3][0]));
    else if (k == 1) v = fmaxf(fmaxf(shf[0][1], shf[1][1]), fmaxf(shf[2][1], shf[3][1]));
    else if (k == 2) v = fminf(fminf(shf[0][2], shf[1][2]), fminf(shf[2][2], shf[3][2]));
    else             v = fmaxf(fmaxf(shf[0][3], shf[1][3]), fmaxf(shf[2][3], shf[3][3]));
    QRmm[k * NB + blockIdx.x] = v;
  }
}

// ============ k_B: reduce partials, Cholesky, scales, init encs
__global__ void __launch_bounds__(256)
k_B(const double* Bpart, const float* QRmm, int n, float* meanL, unsigned* encs) {
  __shared__ double sredd[14];
  __shared__ float sf[4];
  int tid = threadIdx.x;
  if (tid < 14) {
    double s = 0;
    const double* row = Bpart + tid * NB;
    for (int b = 0; b < NB; b++) s += row[b];
    sredd[tid] = s;
  } else if (tid >= 16 && tid < 20) {
    int k = tid - 16;
    const float* row = QRmm + k * NB;
    float v = row[0];
    if (k == 0 || k == 2) { for (int b = 1; b < NB; b++) v = fminf(v, row[b]); }
    else                  { for (int b = 1; b < NB; b++) v = fmaxf(v, row[b]); }
    sf[k] = v;
  }
  __syncthreads();
  if (tid == 0) {
    double mean[4];
    for (int j = 0; j < 4; j++) mean[j] = sredd[j] / (double)n;
    double cov[4][4]; int t4 = 4;
    for (int i = 0; i < 4; i++)
      for (int j = i; j < 4; j++) {
        double c = (sredd[t4] - (double)n * mean[i] * mean[j]) / (double)(n - 1);
        if (i == j) c += 1e-6;
        cov[i][j] = c; cov[j][i] = c; t4++;
      }
    double L[4][4] = {};
    for (int i = 0; i < 4; i++)
      for (int j = 0; j <= i; j++) {
        double s = cov[i][j];
        for (int k = 0; k < j; k++) s -= L[i][k] * L[j][k];
        if (i == j) L[i][j] = sqrt(s);
        else        L[i][j] = s / L[j][j];
      }
    for (int i = 0; i < 4; i++) {
      meanL[i] = (float)mean[i];
      for (int j = 0; j < 4; j++) meanL[4 + i*4 + j] = (float)L[i][j];
    }
    float qlo = sf[0], qhi = sf[1], rlo = sf[2], rhi = sf[3];
    meanL[20] = qlo; meanL[21] = (float)BINS / (qhi - qlo);
    meanL[22] = rlo; meanL[23] = (float)BINS / (rhi - rlo);
    encs[0] = 0xFFFFFFFFu; encs[1] = 0u;
  }
}

// ============ k_C: sample min/max (2 device atomics per block)
__global__ void __launch_bounds__(256)
k_C(const float* __restrict__ z, int S, const float* meanL, unsigned* encs) {
  __shared__ float sL[16], sM[4];
  if (threadIdx.x < 16) sL[threadIdx.x] = meanL[4 + threadIdx.x];
  if (threadIdx.x < 4)  sM[threadIdx.x] = meanL[threadIdx.x];
  __syncthreads();
  float mn = FLT_MAX, mx = -FLT_MAX;
  const nfloat4* z4 = (const nfloat4*)z;
  int stride = gridDim.x * blockDim.x;
  for (int i = blockIdx.x * blockDim.x + threadIdx.x; i < S; i += stride) {
    nfloat4 zv = z4[i];
    float s0, s1, s2, s3; sample4(zv, sL, sM, s0, s1, s2, s3);
    mn = fminf(mn, fminf(fminf(s0, s1), fminf(s2, s3)));
    mx = fmaxf(mx, fmaxf(fmaxf(s0, s1), fmaxf(s2, s3)));
  }
  for (int o = 32; o > 0; o >>= 1) {
    mn = fminf(mn, __shfl_down(mn, o)); mx = fmaxf(mx, __shfl_down(mx, o));
  }
  __shared__ float shmn[4], shmx[4];
  int lane = threadIdx.x & 63, wid = threadIdx.x >> 6;
  if (lane == 0) { shmn[wid] = mn; shmx[wid] = mx; }
  __syncthreads();
  if (threadIdx.x == 0) {
    mn = fminf(fminf(shmn[0], shmn[1]), fminf(shmn[2], shmn[3]));
    mx = fmaxf(fmaxf(shmx[0], shmx[1]), fmaxf(shmx[2], shmx[3]));
    atomicMin(&encs[0], encf(mn));
    atomicMax(&encs[1], encf(mx));
  }
}

// ============ k_D: partition (blocks 0..255) + marginal hists (256..271)
__global__ void __launch_bounds__(1024)
k_D(const float* __restrict__ z, int S,
    const float* __restrict__ q, const float* __restrict__ r, int n,
    const float* meanL, const unsigned* encs,
    unsigned* keys, unsigned* Cnt, unsigned* Qpart, unsigned* Rpart) {
  int tid = threadIdx.x, bid = blockIdx.x;
  if (bid < NB) {
    // --- partition role: compute flat bins, per-block bucket counts
    __shared__ float sL[16], sM[4], sPar[2];
    __shared__ unsigned cnt[NB];
    if (tid < 16) sL[tid] = meanL[4 + tid];
    if (tid < 4)  sM[tid] = meanL[tid];
    if (tid < NB) cnt[tid] = 0;
    if (tid == 0) {
      float lo = decf(encs[0]), hi = decf(encs[1]);
      sPar[0] = lo; sPar[1] = (float)BINS / (hi - lo);
    }
    __syncthreads();
    float lo = sPar[0], sc = sPar[1];
    const nfloat4* z4 = (const nfloat4*)z;
    int chunk = (S + NB - 1) / NB;
    int a0 = bid * chunk, a1 = min(a0 + chunk, S);
    for (int i = a0 + tid; i < a1; i += 1024) {
      nfloat4 zv = z4[i];
      float s0, s1, s2, s3; sample4(zv, sL, sM, s0, s1, s2, s3);
      int i0 = min(max((int)floorf((s0 - lo) * sc), 0), BINS - 1);
      int i1 = min(max((int)floorf((s1 - lo) * sc), 0), BINS - 1);
      int i2 = min(max((int)floorf((s2 - lo) * sc), 0), BINS - 1);
      int i3 = min(max((int)floorf((s3 - lo) * sc), 0), BINS - 1);
      unsigned flat = (unsigned)(((i0*BINS + i1)*BINS + i2)*BINS + i3);
      keys[i] = flat;
      atomicAdd(&cnt[flat & 255u], 1u);
    }
    __syncthreads();
    if (tid < NB) Cnt[bid * NB + tid] = cnt[tid];
  } else {
    // --- marginal histogram role (16 blocks, partial hists, no global atomics)
    __shared__ int shQ[2500];
    __shared__ int shR[2500];
    int qb = bid - NB;
    for (int i = tid; i < 2500; i += 1024) { shQ[i] = 0; shR[i] = 0; }
    __syncthreads();
    float qlo = meanL[20], qsc = meanL[21], rlo = meanL[22], rsc = meanL[23];
    int stride = NQRB * 1024;
    for (int i = qb * 1024 + tid; i < n; i += stride) {
      float2 qv = ((const float2*)q)[i];
      float2 rv = ((const float2*)r)[i];
      int a = min(max((int)floorf((qv.x - qlo) * qsc), 0), BINS - 1);
      int b = min(max((int)floorf((qv.y - qlo) * qsc), 0), BINS - 1);
      atomicAdd(&shQ[a*BINS + b], 1);
      a = min(max((int)floorf((rv.x - rlo) * rsc), 0), BINS - 1);
      b = min(max((int)floorf((rv.y - rlo) * rsc), 0), BINS - 1);
      atomicAdd(&shR[a*BINS + b], 1);
    }
    __syncthreads();
    for (int i = tid; i < 2500; i += 1024) {
      Qpart[qb*2500 + i] = (unsigned)shQ[i];
      Rpart[qb*2500 + i] = (unsigned)shR[i];
    }
  }
}

// ============ k_F: block-local counting sort -> coalesced bucket scatter
__global__ void __launch_bounds__(1024)
k_F(const unsigned* __restrict__ keys, int S, const unsigned* __restrict__ Cnt,
    unsigned short* __restrict__ payload) {
  __shared__ unsigned keyBuf[KCAP];        // 31744 B
  __shared__ unsigned short pays[KCAP];    // 15872 B
  __shared__ unsigned sA[NB], lbase[NB], gbase[NB], cursor[NB];
  int tid = threadIdx.x, bid = blockIdx.x;
  // column sums (all rows) + partial sums (rows < bid), coalesced row-major
  unsigned cs = 0, wsv = 0, myc = 0;
  if (tid < NB) {
    for (int rr = 0; rr < NB; rr++) {
      unsigned c = Cnt[rr * NB + tid];
      cs += c;
      if (rr < bid) wsv += c;
      if (rr == bid) myc = c;
    }
    sA[tid] = cs;
  }
  __syncthreads();
  // inclusive scan of sA -> bucketBase (exclusive) ; gbase = + wsv
  for (int off = 1; off < NB; off <<= 1) {
    unsigned x = (tid < NB && tid >= off) ? sA[tid - off] : 0u;
    __syncthreads();
    if (tid < NB) sA[tid] += x;
    __syncthreads();
  }
  if (tid < NB) { gbase[tid] = (sA[tid] - cs) + wsv; cursor[tid] = 0; sA[tid] = myc; }
  __syncthreads();
  // inclusive scan of own-row counts -> lbase (exclusive)
  for (int off = 1; off < NB; off <<= 1) {
    unsigned x = (tid < NB && tid >= off) ? sA[tid - off] : 0u;
    __syncthreads();
    if (tid < NB) sA[tid] += x;
    __syncthreads();
  }
  if (tid < NB) lbase[tid] = sA[tid] - myc;
  __syncthreads();
  // load own chunk of keys, sort into pays by bucket (LDS only)
  int chunk = (S + NB - 1) / NB;
  int a0 = bid * chunk, a1 = min(a0 + chunk, S);
  int len = a1 - a0;
  for (int j = tid; j < len; j += 1024) keyBuf[j] = keys[a0 + j];
  __syncthreads();
  for (int j = tid; j < len; j += 1024) {
    unsigned k = keyBuf[j];
    unsigned b = k & 255u;
    unsigned pos = lbase[b] + atomicAdd(&cursor[b], 1u);
    pays[pos] = (unsigned short)(k >> 8);
  }
  __syncthreads();
  // coalesced write-out: position p -> bucket via binary search on lbase
  for (int p = tid; p < len; p += 1024) {
    int b = 0;
    #pragma unroll
    for (int step = 128; step > 0; step >>= 1)
      if (b + step < NB && lbase[b + step] <= (unsigned)p) b += step;
    payload[gbase[b] + ((unsigned)p - lbase[b])] = pays[p];
  }
}

// ============ k_G: per-bucket LDS histogram (u16-packed) + entropy partial
__global__ void __launch_bounds__(1024)
k_G(const unsigned short* __restrict__ payload, const unsigned* __restrict__ Cnt,
    double* sumJpart) {
  __shared__ unsigned shist[SWORDS];   // 48832 B
  __shared__ unsigned sA[NB], sB[NB];
  __shared__ double sredd[16];
  __shared__ unsigned sbt[2];
  int tid = threadIdx.x, bid = blockIdx.x;
  unsigned cs = 0;
  if (tid < NB) {
    for (int rr = 0; rr < NB; rr++) cs += Cnt[rr * NB + tid];
    sA[tid] = cs; sB[tid] = cs;
  }
  __syncthreads();
  for (int off = 1; off < NB; off <<= 1) {
    unsigned x = (tid < NB && tid >= off) ? sA[tid - off] : 0u;
    __syncthreads();
    if (tid < NB) sA[tid] += x;
    __syncthreads();
  }
  if (tid == 0) { sbt[0] = sA[bid] - sB[bid]; sbt[1] = sB[bid]; }  // base, tot
  __syncthreads();
  unsigned base = sbt[0], tot = sbt[1];
  for (int i = tid; i < SWORDS; i += 1024) shist[i] = 0u;
  __syncthreads();
  for (unsigned k = tid; k < tot; k += 1024) {
    unsigned p = payload[base + k];   // < 24415
    atomicAdd(&shist[p >> 1], (p & 1u) ? 65536u : 1u);
  }
  __syncthreads();
  double local = 0.0;
  for (int i = tid; i < SWORDS; i += 1024) {
    unsigned w = shist[i];
    unsigned c0 = w & 0xFFFFu, c1 = w >> 16;
    if (c0 > 1) local += (double)c0 * log((double)c0);
    if (c1 > 1) local += (double)c1 * log((double)c1);
  }
  int lane = tid & 63, wid = tid >> 6;
  for (int o = 32; o > 0; o >>= 1) local += __shfl_down(local, o);
  if (lane == 0) sredd[wid] = local;
  __syncthreads();
  if (tid == 0) {
    double s = 0; for (int w = 0; w < 16; w++) s += sredd[w];
    sumJpart[bid] = s;
  }
}

// ============ k_H: final reduction + output
__global__ void __launch_bounds__(1024)
k_H(const double* __restrict__ sumJpart,
    const unsigned* __restrict__ Qpart, const unsigned* __restrict__ Rpart,
    int n, int S, float* out) {
  __shared__ double sredd[48];
  int tid = threadIdx.x, lane = tid & 63, wid = tid >> 6;
  double v = (tid < NB) ? sumJpart[tid] : 0.0;
  for (int o = 32; o > 0; o >>= 1) v += __shfl_down(v, o);
  if (lane == 0) sredd[wid] = v;
  double lq = 0.0, lr = 0.0;
  for (int bin = tid; bin < 2500; bin += 1024) {
    unsigned cq = 0, cr = 0;
    for (int k = 0; k < NQRB; k++) { cq += Qpart[k*2500 + bin]; cr += Rpart[k*2500 + bin]; }
    if (cq > 1) lq += (double)cq * log((double)cq);
    if (cr > 1) lr += (double)cr * log((double)cr);
  }
  for (int o = 32; o > 0; o >>= 1) { lq += __shfl_down(lq, o); lr += __shfl_down(lr, o); }
  if (lane == 0) { sredd[16 + wid] = lq; sredd[32 + wid] = lr; }
  __syncthreads();
  if (tid == 0) {
    double sJ = 0, sq = 0, sr = 0;
    for (int w = 0; w < 16; w++) { sJ += sredd[w]; sq += sredd[16+w]; sr += sredd[32+w]; }
    double HT = log((double)n) - sq / (double)n;
    double HI = log((double)n) - sr / (double)n;
    double HJ = log((double)S) - sJ / (double)S;
    double val = HJ / (HT + HI);
    val = val < 0.0 ? 0.0 : (val > 1.0 ? 1.0 : val);
    out[0] = (float)val;
  }
}

extern "C" void kernel_launch(void* const* d_in, const int* in_sizes, int n_in,
                              void* d_out, int out_size, void* d_ws, size_t ws_size,
                              hipStream_t stream) {
  const float* q = (const float*)d_in[0];
  const float* r = (const float*)d_in[1];
  const float* z = (const float*)d_in[2];
  int N = in_sizes[0] / 2;   // 200000 rows
  int S = in_sizes[2] / 4;   // 2000000 samples

  // workspace layout (bytes), total ~12.6 MB:
  char* base = (char*)d_ws;
  double*   Bpart    = (double*)base;                     //     0: [14][256]
  float*    QRmm     = (float*)(base + 28672);            // 28672: [4][256]
  float*    meanL    = (float*)(base + 32768);            // 32768: [24]
  unsigned* encs     = (unsigned*)(base + 32896);         // 32896: [2]
  double*   sumJpart = (double*)(base + 33024);           // 33024: [256]
  unsigned* Qpart    = (unsigned*)(base + 35072);         // 35072: [16][2500]
  unsigned* Rpart    = (unsigned*)(base + 195072);        // [16][2500]
  unsigned* Cnt      = (unsigned*)(base + 355072);        // [256][256]
  unsigned* keys     = (unsigned*)(base + 617216);        // [2M] (8 MB)
  unsigned short* payload = (unsigned short*)(base + 8617216); // [2M] (4 MB)

  k_A<<<NB,  256, 0, stream>>>(q, r, N, Bpart, QRmm);
  k_B<<<1,   256, 0, stream>>>(Bpart, QRmm, N, meanL, encs);
  k_C<<<1024,256, 0, stream>>>(z, S, meanL, encs);
  k_D<<<NB + NQRB, 1024, 0, stream>>>(z, S, q, r, N, meanL, encs,
                                      keys, Cnt, Qpart, Rpart);
  k_F<<<NB, 1024, 0, stream>>>(keys, S, Cnt, payload);
  k_G<<<NB, 1024, 0, stream>>>(payload, Cnt, sumJpart);
  k_H<<<1,  1024, 0, stream>>>(sumJpart, Qpart, Rpart, N, S, (float*)d_out);
}

// Round 7
// 153.700 us; speedup vs baseline: 2.3558x; 1.3208x over previous
//
#include <hip/hip_runtime.h>
#include <cfloat>
#include <math.h>

#define BINS   50
#define NB     256          // buckets AND partition blocks
#define NQRB   16           // extra blocks doing marginal histograms
#define SWORDS 12208        // ceil(24415/2) u16-packed slice bins (payload = flat>>8 < 24415)
#define KCAP   7936         // >= ceil(2e6/256) = 7813 keys per block

typedef float nfloat4 __attribute__((ext_vector_type(4)));

// ---- monotone float<->uint encoding for atomic min/max on floats ----
__device__ __forceinline__ unsigned encf(float f) {
  unsigned u = __float_as_uint(f);
  return (u & 0x80000000u) ? ~u : (u | 0x80000000u);
}
__device__ __forceinline__ float decf(unsigned u) {
  unsigned v = (u & 0x80000000u) ? (u & 0x7FFFFFFFu) : ~u;
  return __uint_as_float(v);
}

// samples = z @ L^T + mean (bit-identical to all passing rounds)
__device__ __forceinline__ void sample4(nfloat4 zv, const float* L, const float* M,
                                        float& s0, float& s1, float& s2, float& s3) {
  s0 = L[0] * zv.x + M[0];
  s1 = fmaf(L[5], zv.y, L[4] * zv.x) + M[1];
  s2 = fmaf(L[10], zv.z, fmaf(L[9], zv.y, L[8] * zv.x)) + M[2];
  s3 = fmaf(L[15], zv.w, fmaf(L[14], zv.z, fmaf(L[13], zv.y, L[12] * zv.x))) + M[3];
}

// shared reduce helper: waves 0..13 sum Bpart rows -> sD[14];
// waves 14,15 min/max QRmm rows -> sQR[4]. Then thread 0 Cholesky -> sML[24].
__device__ __forceinline__ void reduce_and_chol(const double* Bpart, const float* QRmm,
                                                int n, double* sD, float* sQR, float* sML) {
  int tid = threadIdx.x, ln = tid & 63, wv = tid >> 6;
  if (wv < 14) {
    double s = 0;
    for (int b = ln; b < NB; b += 64) s += Bpart[wv * NB + b];
    for (int o = 32; o > 0; o >>= 1) s += __shfl_down(s, o);
    if (ln == 0) sD[wv] = s;
  } else {
    int k0 = (wv == 14) ? 0 : 2;
    for (int k2 = k0; k2 < k0 + 2; k2++) {
      bool ismn = (k2 == 0) || (k2 == 2);
      float v = ismn ? FLT_MAX : -FLT_MAX;
      for (int b = ln; b < NB; b += 64) {
        float x = QRmm[k2 * NB + b];
        v = ismn ? fminf(v, x) : fmaxf(v, x);
      }
      for (int o = 32; o > 0; o >>= 1) {
        float x = __shfl_down(v, o);
        v = ismn ? fminf(v, x) : fmaxf(v, x);
      }
      if (ln == 0) sQR[k2] = v;
    }
  }
  __syncthreads();
  if (tid == 0) {
    double mean[4];
    for (int j = 0; j < 4; j++) mean[j] = sD[j] / (double)n;
    double cov[4][4]; int t4 = 4;
    for (int i = 0; i < 4; i++)
      for (int j = i; j < 4; j++) {
        double c = (sD[t4] - (double)n * mean[i] * mean[j]) / (double)(n - 1);
        if (i == j) c += 1e-6;
        cov[i][j] = c; cov[j][i] = c; t4++;
      }
    double L[4][4] = {};
    for (int i = 0; i < 4; i++)
      for (int j = 0; j <= i; j++) {
        double s = cov[i][j];
        for (int k = 0; k < j; k++) s -= L[i][k] * L[j][k];
        if (i == j) L[i][j] = sqrt(s);
        else        L[i][j] = s / L[j][j];
      }
    for (int i = 0; i < 4; i++) {
      sML[i] = (float)mean[i];
      for (int j = 0; j < 4; j++) sML[4 + i*4 + j] = (float)L[i][j];
    }
    float qlo = sQR[0], qhi = sQR[1], rlo = sQR[2], rhi = sQR[3];
    sML[20] = qlo; sML[21] = (float)BINS / (qhi - qlo);
    sML[22] = rlo; sML[23] = (float)BINS / (rhi - rlo);
  }
  __syncthreads();
}

// ============ k_A: cov raw moments + q/r min-max partials; init encs/ticket
__global__ void __launch_bounds__(256)
k_A(const float* __restrict__ q, const float* __restrict__ r, int n,
    double* Bpart, float* QRmm, unsigned* encs, unsigned* ticket) {
  double a[14] = {0,0,0,0,0,0,0,0,0,0,0,0,0,0};
  float qmn = FLT_MAX, qmx = -FLT_MAX, rmn = FLT_MAX, rmx = -FLT_MAX;
  int stride = gridDim.x * blockDim.x;
  for (int i = blockIdx.x * blockDim.x + threadIdx.x; i < n; i += stride) {
    float2 qv = ((const float2*)q)[i];
    float2 rv = ((const float2*)r)[i];
    qmn = fminf(qmn, fminf(qv.x, qv.y)); qmx = fmaxf(qmx, fmaxf(qv.x, qv.y));
    rmn = fminf(rmn, fminf(rv.x, rv.y)); rmx = fmaxf(rmx, fmaxf(rv.x, rv.y));
    double x0 = qv.x, x1 = qv.y, x2 = rv.x, x3 = rv.y;
    a[0] += x0; a[1] += x1; a[2] += x2; a[3] += x3;
    a[4] += x0*x0; a[5] += x0*x1; a[6] += x0*x2; a[7] += x0*x3;
    a[8] += x1*x1; a[9] += x1*x2; a[10] += x1*x3;
    a[11] += x2*x2; a[12] += x2*x3; a[13] += x3*x3;
  }
  __shared__ double sh[4][14];
  __shared__ float shf[4][4];
  int lane = threadIdx.x & 63, wid = threadIdx.x >> 6;
  for (int j = 0; j < 14; j++) {
    double v = a[j];
    for (int o = 32; o > 0; o >>= 1) v += __shfl_down(v, o);
    if (lane == 0) sh[wid][j] = v;
  }
  for (int o = 32; o > 0; o >>= 1) {
    qmn = fminf(qmn, __shfl_down(qmn, o)); qmx = fmaxf(qmx, __shfl_down(qmx, o));
    rmn = fminf(rmn, __shfl_down(rmn, o)); rmx = fmaxf(rmx, __shfl_down(rmx, o));
  }
  if (lane == 0) { shf[wid][0] = qmn; shf[wid][1] = qmx; shf[wid][2] = rmn; shf[wid][3] = rmx; }
  __syncthreads();
  if (threadIdx.x < 14) {
    double t = sh[0][threadIdx.x] + sh[1][threadIdx.x] + sh[2][threadIdx.x] + sh[3][threadIdx.x];
    Bpart[threadIdx.x * NB + blockIdx.x] = t;
  } else if (threadIdx.x >= 16 && threadIdx.x < 20) {
    int k = threadIdx.x - 16;
    float v;
    if (k == 0)      v = fminf(fminf(shf[0][0], shf[1][0]), fminf(shf[2][0], shf[3][0]));
    else if (k == 1) v = fmaxf(fmaxf(shf[0][1], shf[1][1]), fmaxf(shf[2][1], shf[3][1]));
    else if (k == 2) v = fminf(fminf(shf[0][2], shf[1][2]), fminf(shf[2][2], shf[3][2]));
    else             v = fmaxf(fmaxf(shf[0][3], shf[1][3]), fmaxf(shf[2][3], shf[3][3]));
    QRmm[k * NB + blockIdx.x] = v;
  } else if (blockIdx.x == 0 && threadIdx.x == 32) {
    encs[0] = 0xFFFFFFFFu; encs[1] = 0u;
    ticket[0] = 0u;
  }
}

// ============ k_C: redundant reduce+Cholesky, then sample min/max
__global__ void __launch_bounds__(1024)
k_C(const double* __restrict__ Bpart, const float* __restrict__ QRmm,
    const float* __restrict__ z, int S, int n, float* meanL, unsigned* encs) {
  __shared__ double sD[14];
  __shared__ float sQR[4];
  __shared__ float sML[24];
  reduce_and_chol(Bpart, QRmm, n, sD, sQR, sML);
  if (threadIdx.x == 0) {     // publish for k_D (identical value across blocks)
    for (int i = 0; i < 24; i++) meanL[i] = sML[i];
  }
  float l[16], m[4];
  for (int i = 0; i < 16; i++) l[i] = sML[4 + i];
  for (int i = 0; i < 4;  i++) m[i] = sML[i];
  float mn = FLT_MAX, mx = -FLT_MAX;
  const nfloat4* z4 = (const nfloat4*)z;
  int stride = gridDim.x * blockDim.x;
  for (int i = blockIdx.x * blockDim.x + threadIdx.x; i < S; i += stride) {
    nfloat4 zv = z4[i];
    float s0, s1, s2, s3; sample4(zv, l, m, s0, s1, s2, s3);
    mn = fminf(mn, fminf(fminf(s0, s1), fminf(s2, s3)));
    mx = fmaxf(mx, fmaxf(fmaxf(s0, s1), fmaxf(s2, s3)));
  }
  for (int o = 32; o > 0; o >>= 1) {
    mn = fminf(mn, __shfl_down(mn, o)); mx = fmaxf(mx, __shfl_down(mx, o));
  }
  __shared__ float shmn[16], shmx[16];
  int lane = threadIdx.x & 63, wid = threadIdx.x >> 6;
  if (lane == 0) { shmn[wid] = mn; shmx[wid] = mx; }
  __syncthreads();
  if (threadIdx.x == 0) {
    for (int w = 1; w < 16; w++) { mn = fminf(mn, shmn[w]); mx = fmaxf(mx, shmx[w]); }
    mn = fminf(mn, shmn[0]); mx = fmaxf(mx, shmx[0]);
    atomicMin(&encs[0], encf(mn));
    atomicMax(&encs[1], encf(mx));
  }
}

// ============ k_D: partition (blocks 0..255) + marginal hists (256..271)
__global__ void __launch_bounds__(1024)
k_D(const float* __restrict__ z, int S,
    const float* __restrict__ q, const float* __restrict__ r, int n,
    const float* __restrict__ meanL, const unsigned* __restrict__ encs,
    unsigned* keys, unsigned* Cnt, unsigned* Qpart, unsigned* Rpart) {
  int tid = threadIdx.x, bid = blockIdx.x;
  if (bid < NB) {
    __shared__ float sL[16], sM[4], sPar[2];
    __shared__ unsigned cnt[NB];
    if (tid < 16) sL[tid] = meanL[4 + tid];
    if (tid < 4)  sM[tid] = meanL[tid];
    if (tid < NB) cnt[tid] = 0;
    if (tid == 0) {
      float lo = decf(encs[0]), hi = decf(encs[1]);
      sPar[0] = lo; sPar[1] = (float)BINS / (hi - lo);
    }
    __syncthreads();
    float lo = sPar[0], sc = sPar[1];
    const nfloat4* z4 = (const nfloat4*)z;
    int chunk = (S + NB - 1) / NB;
    int a0 = bid * chunk, a1 = min(a0 + chunk, S);
    for (int i = a0 + tid; i < a1; i += 1024) {
      nfloat4 zv = z4[i];
      float s0, s1, s2, s3; sample4(zv, sL, sM, s0, s1, s2, s3);
      int i0 = min(max((int)floorf((s0 - lo) * sc), 0), BINS - 1);
      int i1 = min(max((int)floorf((s1 - lo) * sc), 0), BINS - 1);
      int i2 = min(max((int)floorf((s2 - lo) * sc), 0), BINS - 1);
      int i3 = min(max((int)floorf((s3 - lo) * sc), 0), BINS - 1);
      unsigned flat = (unsigned)(((i0*BINS + i1)*BINS + i2)*BINS + i3);
      keys[i] = flat;
      atomicAdd(&cnt[flat & 255u], 1u);
    }
    __syncthreads();
    if (tid < NB) Cnt[bid * NB + tid] = cnt[tid];
  } else {
    __shared__ int shQ[2500];
    __shared__ int shR[2500];
    int qb = bid - NB;
    for (int i = tid; i < 2500; i += 1024) { shQ[i] = 0; shR[i] = 0; }
    __syncthreads();
    float qlo = meanL[20], qsc = meanL[21], rlo = meanL[22], rsc = meanL[23];
    int stride = NQRB * 1024;
    for (int i = qb * 1024 + tid; i < n; i += stride) {
      float2 qv = ((const float2*)q)[i];
      float2 rv = ((const float2*)r)[i];
      int a = min(max((int)floorf((qv.x - qlo) * qsc), 0), BINS - 1);
      int b = min(max((int)floorf((qv.y - qlo) * qsc), 0), BINS - 1);
      atomicAdd(&shQ[a*BINS + b], 1);
      a = min(max((int)floorf((rv.x - rlo) * rsc), 0), BINS - 1);
      b = min(max((int)floorf((rv.y - rlo) * rsc), 0), BINS - 1);
      atomicAdd(&shR[a*BINS + b], 1);
    }
    __syncthreads();
    for (int i = tid; i < 2500; i += 1024) {
      Qpart[qb*2500 + i] = (unsigned)shQ[i];
      Rpart[qb*2500 + i] = (unsigned)shR[i];
    }
  }
}

// ============ k_F: block-local counting sort -> coalesced bucket scatter
__global__ void __launch_bounds__(1024)
k_F(const unsigned* __restrict__ keys, int S, const unsigned* __restrict__ Cnt,
    unsigned short* __restrict__ payload) {
  __shared__ unsigned keyBuf[KCAP];          // 31744 B (aliased as scratch early)
  __shared__ unsigned short pays[KCAP];      // 15872 B
  __shared__ unsigned char bbuf[KCAP];       // 7936 B
  __shared__ unsigned sA[NB], lbase[NB], gbase[NB], cursor[NB];  // 4096 B
  int tid = threadIdx.x, bid = blockIdx.x;
  int t = tid & 255, tq = tid >> 8;          // 4-way row split
  // column partial sums over Cnt rows (cs = all rows, wsv = rows < bid)
  unsigned* scratch = keyBuf;                // [4][256][2]
  unsigned csp = 0, wsp = 0;
  for (int rr = tq * 64; rr < (tq + 1) * 64; rr++) {
    unsigned c = Cnt[rr * NB + t];
    csp += c;
    if (rr < bid) wsp += c;
  }
  scratch[(tq * 256 + t) * 2]     = csp;
  scratch[(tq * 256 + t) * 2 + 1] = wsp;
  __syncthreads();
  unsigned cs = 0, wsv = 0, myc = 0;
  if (tid < NB) {
    for (int k2 = 0; k2 < 4; k2++) {
      cs  += scratch[(k2 * 256 + tid) * 2];
      wsv += scratch[(k2 * 256 + tid) * 2 + 1];
    }
    myc = Cnt[bid * NB + tid];
    sA[tid] = cs;
  }
  __syncthreads();
  for (int off = 1; off < NB; off <<= 1) {           // scan cs -> bucket base
    unsigned x = (tid < NB && tid >= off) ? sA[tid - off] : 0u;
    __syncthreads();
    if (tid < NB) sA[tid] += x;
    __syncthreads();
  }
  if (tid < NB) { gbase[tid] = (sA[tid] - cs) + wsv; sA[tid] = myc; cursor[tid] = 0; }
  __syncthreads();
  for (int off = 1; off < NB; off <<= 1) {           // scan myc -> local base
    unsigned x = (tid < NB && tid >= off) ? sA[tid - off] : 0u;
    __syncthreads();
    if (tid < NB) sA[tid] += x;
    __syncthreads();
  }
  if (tid < NB) lbase[tid] = sA[tid] - myc;
  __syncthreads();
  // load own chunk (overwrites scratch region — safe after barrier)
  int chunk = (S + NB - 1) / NB;
  int a0 = bid * chunk, a1 = min(a0 + chunk, S);
  int len = a1 - a0;
  for (int j = tid; j < len; j += 1024) keyBuf[j] = keys[a0 + j];
  __syncthreads();
  for (int j = tid; j < len; j += 1024) {
    unsigned k = keyBuf[j];
    unsigned b = k & 255u;
    unsigned pos = lbase[b] + atomicAdd(&cursor[b], 1u);
    pays[pos] = (unsigned short)(k >> 8);
    bbuf[pos] = (unsigned char)b;
  }
  __syncthreads();
  for (int p = tid; p < len; p += 1024) {
    unsigned b = bbuf[p];
    payload[gbase[b] + ((unsigned)p - lbase[b])] = pays[p];
  }
}

// ============ k_G: per-bucket LDS histogram + entropy; last block finalizes
__global__ void __launch_bounds__(1024)
k_G(const unsigned short* __restrict__ payload, const unsigned* __restrict__ Cnt,
    const unsigned* __restrict__ Qpart, const unsigned* __restrict__ Rpart,
    double* sumJpart, unsigned* ticket, int n, int S, float* out) {
  __shared__ unsigned shist[SWORDS];   // 48832 B (aliased as scratch early)
  __shared__ unsigned sA2[NB], sB2[NB];
  __shared__ double sredd[48];
  __shared__ unsigned isLast;
  int tid = threadIdx.x, bid = blockIdx.x;
  int t = tid & 255, tq = tid >> 8;
  unsigned* scratch = shist;           // [4][256]
  unsigned csp = 0;
  for (int rr = tq * 64; rr < (tq + 1) * 64; rr++) csp += Cnt[rr * NB + t];
  scratch[tq * 256 + t] = csp;
  __syncthreads();
  unsigned cs = 0;
  if (tid < NB) {
    for (int k2 = 0; k2 < 4; k2++) cs += scratch[k2 * 256 + tid];
    sA2[tid] = cs; sB2[tid] = cs;
  }
  __syncthreads();
  for (int off = 1; off < NB; off <<= 1) {
    unsigned x = (tid < NB && tid >= off) ? sA2[tid - off] : 0u;
    __syncthreads();
    if (tid < NB) sA2[tid] += x;
    __syncthreads();
  }
  unsigned base = sA2[bid] - sB2[bid];
  unsigned tot  = sB2[bid];
  __syncthreads();
  for (int i = tid; i < SWORDS; i += 1024) shist[i] = 0u;
  __syncthreads();
  for (unsigned k = tid; k < tot; k += 1024) {
    unsigned p = payload[base + k];    // < 24415
    atomicAdd(&shist[p >> 1], (p & 1u) ? 65536u : 1u);
  }
  __syncthreads();
  double local = 0.0;
  for (int i = tid; i < SWORDS; i += 1024) {
    unsigned w = shist[i];
    unsigned c0 = w & 0xFFFFu, c1 = w >> 16;
    if (c0 > 1) local += (double)c0 * log((double)c0);
    if (c1 > 1) local += (double)c1 * log((double)c1);
  }
  int lane = tid & 63, wid = tid >> 6;
  for (int o = 32; o > 0; o >>= 1) local += __shfl_down(local, o);
  if (lane == 0) sredd[wid] = local;
  __syncthreads();
  if (tid == 0) {
    double s = 0; for (int w = 0; w < 16; w++) s += sredd[w];
    sumJpart[bid] = s;
    __threadfence();
    isLast = (atomicAdd(ticket, 1u) == NB - 1) ? 1u : 0u;
  }
  __syncthreads();
  if (!isLast) return;
  // ---------- last block: final reduction + output ----------
  __threadfence();
  double v = 0.0;
  if (tid < NB)
    v = __hip_atomic_load(&sumJpart[tid], __ATOMIC_RELAXED, __HIP_MEMORY_SCOPE_AGENT);
  for (int o = 32; o > 0; o >>= 1) v += __shfl_down(v, o);
  if (lane == 0) sredd[wid] = v;
  double lq = 0.0, lr = 0.0;
  for (int bin = tid; bin < 2500; bin += 1024) {
    unsigned cq = 0, cr = 0;
    for (int k = 0; k < NQRB; k++) { cq += Qpart[k*2500 + bin]; cr += Rpart[k*2500 + bin]; }
    if (cq > 1) lq += (double)cq * log((double)cq);
    if (cr > 1) lr += (double)cr * log((double)cr);
  }
  for (int o = 32; o > 0; o >>= 1) { lq += __shfl_down(lq, o); lr += __shfl_down(lr, o); }
  if (lane == 0) { sredd[16 + wid] = lq; sredd[32 + wid] = lr; }
  __syncthreads();
  if (tid == 0) {
    double sJ = 0, sq = 0, sr = 0;
    for (int w = 0; w < 16; w++) { sJ += sredd[w]; sq += sredd[16+w]; sr += sredd[32+w]; }
    double HT = log((double)n) - sq / (double)n;
    double HI = log((double)n) - sr / (double)n;
    double HJ = log((double)S) - sJ / (double)S;
    double val = HJ / (HT + HI);
    val = val < 0.0 ? 0.0 : (val > 1.0 ? 1.0 : val);
    out[0] = (float)val;
  }
}

extern "C" void kernel_launch(void* const* d_in, const int* in_sizes, int n_in,
                              void* d_out, int out_size, void* d_ws, size_t ws_size,
                              hipStream_t stream) {
  const float* q = (const float*)d_in[0];
  const float* r = (const float*)d_in[1];
  const float* z = (const float*)d_in[2];
  int N = in_sizes[0] / 2;   // 200000 rows
  int S = in_sizes[2] / 4;   // 2000000 samples

  // workspace layout (bytes), total ~12.6 MB:
  char* base = (char*)d_ws;
  double*   Bpart    = (double*)base;                     //      0: [14][256]
  float*    QRmm     = (float*)(base + 28672);            //  28672: [4][256]
  float*    meanL    = (float*)(base + 32768);            //  32768: [24]
  unsigned* encs     = (unsigned*)(base + 32896);         //  32896: [2]
  unsigned* ticket   = (unsigned*)(base + 32904);         //  32904: [1]
  double*   sumJpart = (double*)(base + 33024);           //  33024: [256]
  unsigned* Qpart    = (unsigned*)(base + 35072);         //  35072: [16][2500]
  unsigned* Rpart    = (unsigned*)(base + 195072);        // [16][2500]
  unsigned* Cnt      = (unsigned*)(base + 355072);        // [256][256]
  unsigned* keys     = (unsigned*)(base + 617216);        // [2M] (8 MB)
  unsigned short* payload = (unsigned short*)(base + 8617216); // [2M] (4 MB)

  k_A<<<NB,  256,  0, stream>>>(q, r, N, Bpart, QRmm, encs, ticket);
  k_C<<<NB,  1024, 0, stream>>>(Bpart, QRmm, z, S, N, meanL, encs);
  k_D<<<NB + NQRB, 1024, 0, stream>>>(z, S, q, r, N, meanL, encs,
                                      keys, Cnt, Qpart, Rpart);
  k_F<<<NB, 1024, 0, stream>>>(keys, S, Cnt, payload);
  k_G<<<NB, 1024, 0, stream>>>(payload, Cnt, Qpart, Rpart,
                               sumJpart, ticket, N, S, (float*)d_out);
}